// Round 15
// baseline (418.753 us; speedup 1.0000x reference)
//
#include <hip/hip_runtime.h>
#include <cmath>

#define D 640
#define TEMP_INV (1.0f / 0.07f)

typedef __attribute__((ext_vector_type(8))) short bf16x8;
typedef __attribute__((ext_vector_type(4))) float f32x4;

__device__ __forceinline__ short f2bf(float f) {
    unsigned int u = __float_as_uint(f);
    unsigned int r = (u + 0x7fffu + ((u >> 16) & 1u)) >> 16;   // RNE bf16
    return (short)r;
}

__device__ __forceinline__ void gload_lds16(const void* g, void* l) {
    __builtin_amdgcn_global_load_lds(
        (const __attribute__((address_space(1))) unsigned int*)g,
        (__attribute__((address_space(3))) unsigned int*)l, 16, 0, 0);
}

// ---------------------------------------------------------------- text norm
__global__ void textnorm_k(const float* __restrict__ T, float* __restrict__ tn) {
    int w = threadIdx.x >> 6, lane = threadIdx.x & 63;
    const float* row = T + w * D;
    float v[10]; float ss = 0.f;
#pragma unroll
    for (int i = 0; i < 10; i++) { v[i] = row[lane + 64 * i]; ss += v[i] * v[i]; }
#pragma unroll
    for (int m = 1; m < 64; m <<= 1) ss += __shfl_xor(ss, m, 64);
    float rn = 1.f / fmaxf(sqrtf(ss), 1e-12f);
#pragma unroll
    for (int i = 0; i < 10; i++) tn[w * D + lane + 64 * i] = v[i] * rn;
}

// ---------------- fused: row norm + text score + normalized-bf16 store (padded)
__global__ __launch_bounds__(256) void normstore_k(
    const float* __restrict__ X, int nsrc, int npad, const float* __restrict__ tn,
    float* __restrict__ score_out, short* __restrict__ bf16_out) {
    int wid = blockIdx.x * 4 + (threadIdx.x >> 6);
    int lane = threadIdx.x & 63;
    if (wid >= npad) return;
    const float2* row = (const float2*)(X + (size_t)(wid < nsrc ? wid : 0) * D);
    const float2* t0 = (const float2*)tn;
    const float2* t1 = (const float2*)(tn + D);
    float2 v[5]; float ss = 0.f, d0 = 0.f, d1 = 0.f;
#pragma unroll
    for (int i = 0; i < 5; i++) {
        float2 a = row[lane + 64 * i];
        v[i] = a;
        ss += a.x * a.x + a.y * a.y;
        if (tn) {
            float2 b0 = t0[lane + 64 * i], b1 = t1[lane + 64 * i];
            d0 += a.x * b0.x + a.y * b0.y;
            d1 += a.x * b1.x + a.y * b1.y;
        }
    }
#pragma unroll
    for (int m = 1; m < 64; m <<= 1) {
        ss += __shfl_xor(ss, m, 64);
        if (tn) { d0 += __shfl_xor(d0, m, 64); d1 += __shfl_xor(d1, m, 64); }
    }
    float rn = 1.f / fmaxf(sqrtf(ss), 1e-12f);
    if (score_out && lane == 0)
        score_out[wid] = 1.f / (1.f + expf(-((d1 - d0) * rn) * TEMP_INV));
    if (bf16_out) {
        ushort2* o = (ushort2*)bf16_out;
#pragma unroll
        for (int i = 0; i < 5; i++) {
            ushort2 p;
            p.x = (unsigned short)f2bf(v[i].x * rn);
            p.y = (unsigned short)f2bf(v[i].y * rn);
            o[(size_t)wid * 320 + lane + 64 * i] = p;
        }
    }
}

// ---- 256x256 fine-phase pipelined GEMM + per-unit per-wave max partials
// A: [nrc*256 x 640] bf16; B: [nch*256 x 640] bf16. BK=64, 512 thr, 8 waves
// (2M x 4N), wave-tile 128x64, acc[8][4]. LDS 2buf x (A 32K + B 32K) = 128 KB
// -> 1 block/CU; intra-block phase stagger supplies the overlap (m201).
// Per K-tile: 4 phases {8 ds_read_b128 -> raw s_barrier -> setprio -> 16 MFMA};
// A-halves of kt+1 staged in phase 0, B-halves in phase 1 (issue-early);
// single vmcnt(0) at the K-tile boundary (drain overlapped 2.5-3.5 phases).
// Race-freedom: LDS written only by vmcnt-tracked gload into the other buffer;
// each wave's ds_reads retire (compiler lgkmcnt) before it reaches the boundary
// barrier; boundary vmcnt(0)+barrier seals the swap (r9-verified discipline).
#define BAR() do { __builtin_amdgcn_s_barrier(); asm volatile("" ::: "memory"); } while (0)

#define READA(RH, KB) do { \
    a0 = *(const bf16x8*)(Ah + ((RH)*64 +  0 + l15) * 128 + (KB)); \
    a1 = *(const bf16x8*)(Ah + ((RH)*64 + 16 + l15) * 128 + (KB)); \
    a2 = *(const bf16x8*)(Ah + ((RH)*64 + 32 + l15) * 128 + (KB)); \
    a3 = *(const bf16x8*)(Ah + ((RH)*64 + 48 + l15) * 128 + (KB)); } while (0)

#define READB(KB) do { \
    b0 = *(const bf16x8*)(Bh + (bcol +  0 + l15) * 128 + (KB)); \
    b1 = *(const bf16x8*)(Bh + (bcol + 16 + l15) * 128 + (KB)); \
    b2 = *(const bf16x8*)(Bh + (bcol + 32 + l15) * 128 + (KB)); \
    b3 = *(const bf16x8*)(Bh + (bcol + 48 + l15) * 128 + (KB)); } while (0)

#define MFMA16(RH) do { \
    acc[(RH)*4+0][0] = __builtin_amdgcn_mfma_f32_16x16x32_bf16(a0, b0, acc[(RH)*4+0][0], 0,0,0); \
    acc[(RH)*4+0][1] = __builtin_amdgcn_mfma_f32_16x16x32_bf16(a0, b1, acc[(RH)*4+0][1], 0,0,0); \
    acc[(RH)*4+0][2] = __builtin_amdgcn_mfma_f32_16x16x32_bf16(a0, b2, acc[(RH)*4+0][2], 0,0,0); \
    acc[(RH)*4+0][3] = __builtin_amdgcn_mfma_f32_16x16x32_bf16(a0, b3, acc[(RH)*4+0][3], 0,0,0); \
    acc[(RH)*4+1][0] = __builtin_amdgcn_mfma_f32_16x16x32_bf16(a1, b0, acc[(RH)*4+1][0], 0,0,0); \
    acc[(RH)*4+1][1] = __builtin_amdgcn_mfma_f32_16x16x32_bf16(a1, b1, acc[(RH)*4+1][1], 0,0,0); \
    acc[(RH)*4+1][2] = __builtin_amdgcn_mfma_f32_16x16x32_bf16(a1, b2, acc[(RH)*4+1][2], 0,0,0); \
    acc[(RH)*4+1][3] = __builtin_amdgcn_mfma_f32_16x16x32_bf16(a1, b3, acc[(RH)*4+1][3], 0,0,0); \
    acc[(RH)*4+2][0] = __builtin_amdgcn_mfma_f32_16x16x32_bf16(a2, b0, acc[(RH)*4+2][0], 0,0,0); \
    acc[(RH)*4+2][1] = __builtin_amdgcn_mfma_f32_16x16x32_bf16(a2, b1, acc[(RH)*4+2][1], 0,0,0); \
    acc[(RH)*4+2][2] = __builtin_amdgcn_mfma_f32_16x16x32_bf16(a2, b2, acc[(RH)*4+2][2], 0,0,0); \
    acc[(RH)*4+2][3] = __builtin_amdgcn_mfma_f32_16x16x32_bf16(a2, b3, acc[(RH)*4+2][3], 0,0,0); \
    acc[(RH)*4+3][0] = __builtin_amdgcn_mfma_f32_16x16x32_bf16(a3, b0, acc[(RH)*4+3][0], 0,0,0); \
    acc[(RH)*4+3][1] = __builtin_amdgcn_mfma_f32_16x16x32_bf16(a3, b1, acc[(RH)*4+3][1], 0,0,0); \
    acc[(RH)*4+3][2] = __builtin_amdgcn_mfma_f32_16x16x32_bf16(a3, b2, acc[(RH)*4+3][2], 0,0,0); \
    acc[(RH)*4+3][3] = __builtin_amdgcn_mfma_f32_16x16x32_bf16(a3, b3, acc[(RH)*4+3][3], 0,0,0); } while (0)

__global__ __launch_bounds__(512, 2) void gemm_max8_k(
    const short* __restrict__ A, const short* __restrict__ B,
    int nch, int U, float* __restrict__ partial) {
    __shared__ short L[2][2][2][8192];   // [buf][A/B][half][128 rows x 64 k]
    const int t = threadIdx.x;
    const int g = blockIdx.x & 7, ii = blockIdx.x >> 3;
    const int ulo = (int)(((long long)g * U) >> 3);
    const int uhi = (int)(((long long)(g + 1) * U) >> 3);
    const int u = ulo + ii;
    if (u >= uhi) return;
    const int rc = u / nch, nc = u - rc * nch;
    const int nchq = nch * 4;

    // staging geometry (r11-verified swizzle pair, rescaled): thread t covers
    // row srow = t>>3 (+64 per extra load), byte col (t&7)*16; source pre-XOR.
    const int srow = t >> 3;                               // 0..63
    const int scol = (t & 7) * 16;
    const int gsw = (scol ^ ((srow & 7) << 4)) >> 1;       // shorts

    const int lane = t & 63, wave = t >> 6;
    const int l15 = lane & 15, lhi = lane >> 4;
    const int wr = wave >> 2, wc = wave & 3;               // 2M x 4N waves
    const int xk = (l15 & 7) << 4;                         // read-side swizzle
    const int bcol = (wc & 1) * 64;                        // col base in B-half
    const int kb0 = (lhi * 16) ^ xk;                       // ksub0 byte offset
    const int kb1 = (64 + lhi * 16) ^ xk;                  // ksub1 byte offset

    const short* Asrc = A + ((size_t)rc * 256 + srow) * D + gsw;
    const short* Bsrc = B + ((size_t)nc * 256 + srow) * D + gsw;

    auto stageA = [&](int nb, int kc) {
#pragma unroll
        for (int h = 0; h < 2; h++)
#pragma unroll
            for (int i = 0; i < 2; i++)
                gload_lds16(Asrc + (size_t)(h * 128 + i * 64) * D + kc * 64,
                            (char*)&L[nb][0][h][0] + i * 8192 + (t << 4));
    };
    auto stageB = [&](int nb, int kc) {
#pragma unroll
        for (int h = 0; h < 2; h++)
#pragma unroll
            for (int i = 0; i < 2; i++)
                gload_lds16(Bsrc + (size_t)(h * 128 + i * 64) * D + kc * 64,
                            (char*)&L[nb][1][h][0] + i * 8192 + (t << 4));
    };

    f32x4 acc[8][4];
#pragma unroll
    for (int m = 0; m < 8; m++)
#pragma unroll
        for (int n = 0; n < 4; n++) acc[m][n] = (f32x4){0.f, 0.f, 0.f, 0.f};

    // prologue: K-tile 0 into buf 0
    stageA(0, 0);
    stageB(0, 0);
    asm volatile("s_waitcnt vmcnt(0)" ::: "memory");
    BAR();

    for (int kt = 0; kt < 10; kt++) {
        const int cb = kt & 1, kn = kt + 1;
        const char* Ah = (const char*)&L[cb][0][wr][0];
        const char* Bh = (const char*)&L[cb][1][wc >> 1][0];
        bf16x8 a0, a1, a2, a3, b0, b1, b2, b3;

        // phase 0: rows-half 0, ksub 0; issue next-tile A stages
        READB(kb0); READA(0, kb0);
        if (kn < 10) stageA(kn & 1, kn);
        BAR();
        __builtin_amdgcn_s_setprio(1);
        MFMA16(0);
        __builtin_amdgcn_s_setprio(0);
        BAR();
        // phase 1: rows-half 1, ksub 0 (b reused); issue next-tile B stages
        READA(1, kb0);
        if (kn < 10) stageB(kn & 1, kn);
        BAR();
        __builtin_amdgcn_s_setprio(1);
        MFMA16(1);
        __builtin_amdgcn_s_setprio(0);
        BAR();
        // phase 2: rows-half 0, ksub 1
        READB(kb1); READA(0, kb1);
        BAR();
        __builtin_amdgcn_s_setprio(1);
        MFMA16(0);
        __builtin_amdgcn_s_setprio(0);
        BAR();
        // phase 3: rows-half 1, ksub 1; boundary: drain next-tile stages
        READA(1, kb1);
        BAR();
        __builtin_amdgcn_s_setprio(1);
        MFMA16(1);
        __builtin_amdgcn_s_setprio(0);
        asm volatile("s_waitcnt vmcnt(0)" ::: "memory");
        BAR();
    }

    // epilogue: per-row max over this wave's 64 cols -> partial
#pragma unroll
    for (int rf = 0; rf < 8; rf++)
#pragma unroll
        for (int ri = 0; ri < 4; ri++) {
            float v = fmaxf(fmaxf(acc[rf][0][ri], acc[rf][1][ri]),
                            fmaxf(acc[rf][2][ri], acc[rf][3][ri]));
#pragma unroll
            for (int msk = 1; msk < 16; msk <<= 1)
                v = fmaxf(v, __shfl_xor(v, msk, 64));
            if (l15 == 0) {
                int row = rc * 256 + wr * 128 + rf * 16 + lhi * 4 + ri;
                partial[(size_t)row * nchq + nc * 4 + wc] = v;
            }
        }
}

// ------------------------------------------------ reduce partials -> vas score
__global__ __launch_bounds__(256) void reducemax_k(
    const float* __restrict__ partial, int nchq, int nrows, float* __restrict__ vas) {
    int r = blockIdx.x * 256 + threadIdx.x;
    if (r >= nrows) return;
    float m = -1e30f;
    for (int i = 0; i < nchq; i++) m = fmaxf(m, partial[(size_t)r * nchq + i]);
    vas[r] = (1.0f - m) * 0.5f;
}

// =================== OLD (round-1) fallback path kernels =====================
__global__ __launch_bounds__(256) void rowstats_k(
    const float* __restrict__ X, int nrows, const float* __restrict__ tn,
    float* __restrict__ rnorm_out, float* __restrict__ score_out) {
    int wid = blockIdx.x * 4 + (threadIdx.x >> 6);
    int lane = threadIdx.x & 63;
    if (wid >= nrows) return;
    const float* row = X + (size_t)wid * D;
    float ss = 0.f, d0 = 0.f, d1 = 0.f;
#pragma unroll
    for (int i = 0; i < 10; i++) {
        float v = row[lane + 64 * i];
        ss += v * v;
        if (tn) { d0 += v * tn[lane + 64 * i]; d1 += v * tn[D + lane + 64 * i]; }
    }
#pragma unroll
    for (int m = 1; m < 64; m <<= 1) {
        ss += __shfl_xor(ss, m, 64);
        if (tn) { d0 += __shfl_xor(d0, m, 64); d1 += __shfl_xor(d1, m, 64); }
    }
    if (lane == 0) {
        float rn = 1.f / fmaxf(sqrtf(ss), 1e-12f);
        if (rnorm_out) rnorm_out[wid] = rn;
        if (score_out) score_out[wid] = 1.f / (1.f + expf(-((d1 - d0) * rn) * TEMP_INV));
    }
}

__global__ __launch_bounds__(256) void refnorm_k(
    const float* __restrict__ R, int M, int Mp, short* __restrict__ out) {
    int wid = blockIdx.x * 4 + (threadIdx.x >> 6);
    int lane = threadIdx.x & 63;
    if (wid >= Mp) return;
    const float* row = R + (size_t)(wid < M ? wid : 0) * D;
    float v[10]; float ss = 0.f;
#pragma unroll
    for (int i = 0; i < 10; i++) { v[i] = row[lane + 64 * i]; ss += v[i] * v[i]; }
#pragma unroll
    for (int m = 1; m < 64; m <<= 1) ss += __shfl_xor(ss, m, 64);
    float rn = 1.f / fmaxf(sqrtf(ss), 1e-12f);
#pragma unroll
    for (int i = 0; i < 10; i++) out[(size_t)wid * D + lane + 64 * i] = f2bf(v[i] * rn);
}

#define SA 648
#define SB 72
__global__ __launch_bounds__(256) void maxcos_k(
    const float* __restrict__ X, const float* __restrict__ rnorm,
    const short* __restrict__ refs, int Mp, float* __restrict__ vas_out) {
    __shared__ short Alds[64 * SA];
    __shared__ short Blds[64 * SB];
    const int t = threadIdx.x;
    const size_t rowBase = (size_t)blockIdx.x * 64;
#pragma unroll
    for (int i = 0; i < 20; i++) {
        int c = i * 256 + t;
        int row = c / 80, col = (c % 80) * 8;
        const float* p = X + (rowBase + row) * D + col;
        float rn = rnorm[rowBase + row];
        float4 v0 = *(const float4*)p;
        float4 v1 = *(const float4*)(p + 4);
        bf16x8 s;
        s[0] = f2bf(v0.x * rn); s[1] = f2bf(v0.y * rn);
        s[2] = f2bf(v0.z * rn); s[3] = f2bf(v0.w * rn);
        s[4] = f2bf(v1.x * rn); s[5] = f2bf(v1.y * rn);
        s[6] = f2bf(v1.z * rn); s[7] = f2bf(v1.w * rn);
        *(bf16x8*)&Alds[row * SA + col] = s;
    }
    __syncthreads();
    const int lane = t & 63, wave = t >> 6;
    const int l15 = lane & 15, lhi = lane >> 4;
    const int wr0 = wave * 16;
    float rowmax[4] = {-1e30f, -1e30f, -1e30f, -1e30f};
    for (int m0 = 0; m0 < Mp; m0 += 64) {
        f32x4 zero = {0.f, 0.f, 0.f, 0.f};
        f32x4 acc[4] = {zero, zero, zero, zero};
        for (int ks = 0; ks < 10; ks++) {
            __syncthreads();
#pragma unroll
            for (int c2 = 0; c2 < 2; c2++) {
                int c = c2 * 256 + t;
                int n = c >> 3, kk = (c & 7) * 8;
                const short* g = refs + (size_t)(m0 + n) * D + ks * 64 + kk;
                *(bf16x8*)&Blds[n * SB + kk] = *(const bf16x8*)g;
            }
            __syncthreads();
#pragma unroll
            for (int sub = 0; sub < 2; sub++) {
                bf16x8 a = *(const bf16x8*)&Alds[(wr0 + l15) * SA + ks * 64 + sub * 32 + lhi * 8];
#pragma unroll
                for (int s = 0; s < 4; s++) {
                    bf16x8 b = *(const bf16x8*)&Blds[(s * 16 + l15) * SB + sub * 32 + lhi * 8];
                    acc[s] = __builtin_amdgcn_mfma_f32_16x16x32_bf16(a, b, acc[s], 0, 0, 0);
                }
            }
        }
#pragma unroll
        for (int r = 0; r < 4; r++) {
            float mv = fmaxf(fmaxf(acc[0][r], acc[1][r]), fmaxf(acc[2][r], acc[3][r]));
#pragma unroll
            for (int msk = 1; msk < 16; msk <<= 1) mv = fmaxf(mv, __shfl_xor(mv, msk, 64));
            rowmax[r] = fmaxf(rowmax[r], mv);
        }
    }
    if (l15 == 0) {
#pragma unroll
        for (int r = 0; r < 4; r++) {
            size_t row = rowBase + wr0 + lhi * 4 + r;
            vas_out[row] = (1.0f - rowmax[r]) * 0.5f;
        }
    }
}

// ------------------------------------- harmonic aggregation + fusion + max
__global__ __launch_bounds__(256) void fuse_k(
    const float* __restrict__ imgsc, const float* __restrict__ zs2,
    const float* __restrict__ zs3, const float* __restrict__ vasP,
    const float* __restrict__ vas2, const float* __restrict__ vas3,
    float* __restrict__ multi, float* __restrict__ img_out) {
    int b = blockIdx.x, t = threadIdx.x;
    __shared__ float red[256];
    float few = -1e30f;
    if (t < 225) {
        int i = t / 15, j = t % 15;
        float invz2 = 0.f, invf2 = 0.f; int c2 = 0;
        int ilo = max(0, i - 1), ihi = min(i, 13), jlo = max(0, j - 1), jhi = min(j, 13);
        for (int i0 = ilo; i0 <= ihi; i0++)
            for (int j0 = jlo; j0 <= jhi; j0++) {
                int w = b * 196 + i0 * 14 + j0;
                invz2 += 1.f / zs2[w]; invf2 += 1.f / vas2[w]; c2++;
            }
        float zh2 = (float)c2 / invz2, fh2 = (float)c2 / invf2;
        float invz3 = 0.f, invf3 = 0.f; int c3 = 0;
        ilo = max(0, i - 2); ihi = min(i, 12); jlo = max(0, j - 2); jhi = min(j, 12);
        for (int i0 = ilo; i0 <= ihi; i0++)
            for (int j0 = jlo; j0 <= jhi; j0++) {
                int w = b * 169 + i0 * 13 + j0;
                invz3 += 1.f / zs3[w]; invf3 += 1.f / vas3[w]; c3++;
            }
        float zh3 = (float)c3 / invz3, fh3 = (float)c3 / invf3;
        float is = imgsc[b];
        float zero_shot = 3.f / (1.f / is + 1.f / zh2 + 1.f / zh3);
        float fs0 = vasP[b * 225 + t];
        few = (fs0 + fh2 + fh3) * (1.f / 3.f);
        multi[b * 225 + t] = (zero_shot + few) * 0.5f;
    }
    red[t] = few;
    __syncthreads();
    for (int s = 128; s > 0; s >>= 1) {
        if (t < s) red[t] = fmaxf(red[t], red[t + s]);
        __syncthreads();
    }
    if (t == 0) img_out[b] = (imgsc[b] + red[0]) * 0.5f;
}

// ----------------------------------- bilinear resize 15x15 -> 240x240 (clamp)
__global__ __launch_bounds__(256) void resize_k(
    const float* __restrict__ multi, float* __restrict__ out) {
    int idx = blockIdx.x * 256 + threadIdx.x;
    int x = idx % 240;
    int rest = idx / 240;
    int y = rest % 240;
    int b = rest / 240;
    float sx = (x + 0.5f) * 0.0625f - 0.5f;
    float sy = (y + 0.5f) * 0.0625f - 0.5f;
    sx = fminf(fmaxf(sx, 0.f), 14.f);
    sy = fminf(fmaxf(sy, 0.f), 14.f);
    int x0 = min((int)sx, 13), y0 = min((int)sy, 13);
    float fx = sx - x0, fy = sy - y0;
    const float* m = multi + b * 225;
    float v00 = m[y0 * 15 + x0],      v01 = m[y0 * 15 + x0 + 1];
    float v10 = m[y0 * 15 + 15 + x0], v11 = m[y0 * 15 + 15 + x0 + 1];
    out[idx] = (1.f - fy) * ((1.f - fx) * v00 + fx * v01)
             + fy * ((1.f - fx) * v10 + fx * v11);
}

// ---------------------------------------------------------------------------
extern "C" void kernel_launch(void* const* d_in, const int* in_sizes, int n_in,
                              void* d_out, int out_size, void* d_ws, size_t ws_size,
                              hipStream_t stream) {
    const float* image = (const float*)d_in[0];
    const float* w2    = (const float*)d_in[1];
    const float* w3    = (const float*)d_in[2];
    const float* patch = (const float*)d_in[3];
    const float* text  = (const float*)d_in[4];
    const float* refP  = (const float*)d_in[5];
    const float* ref2  = (const float*)d_in[6];
    const float* ref3  = (const float*)d_in[7];
    float* out_img = (float*)d_out;
    float* out_pix = out_img + 256;

    char* wsb = (char*)d_ws;
    size_t off = 0;
    auto alloc = [&](size_t bytes) -> void* {
        void* p = wsb + off;
        off += (bytes + 255) & ~(size_t)255;
        return p;
    };

    // new-path workspace need (~72.6 MB, below known-safe 80.2 MB floor)
    const size_t NEW_NEED = 72600000;
    if (ws_size >= NEW_NEED) {
        float* tn    = (float*)alloc(2 * 640 * 4);
        float* imgsc = (float*)alloc(256 * 4);
        float* zs2   = (float*)alloc(50176 * 4);
        float* zs3   = (float*)alloc(43264 * 4);
        short* nrefP = (short*)alloc(1024 * 640 * 2);
        short* nref2 = (short*)alloc(1024 * 640 * 2);
        short* nref3 = (short*)alloc(768 * 640 * 2);
        short* Abuf  = (short*)alloc((size_t)50176 * 640 * 2);
        float* partial = (float*)alloc((size_t)50176 * 16 * 4);
        float* vasP  = (float*)alloc(57600 * 4);
        float* vas2  = (float*)alloc(50176 * 4);
        float* vas3  = (float*)alloc(43264 * 4);
        float* multi = (float*)alloc(57600 * 4);

        textnorm_k<<<1, 128, 0, stream>>>(text, tn);
        normstore_k<<<64, 256, 0, stream>>>(image, 256, 256, tn, imgsc, nullptr);
        normstore_k<<<256, 256, 0, stream>>>(refP, 900, 1024, nullptr, nullptr, nrefP);
        normstore_k<<<256, 256, 0, stream>>>(ref2, 784, 1024, nullptr, nullptr, nref2);
        normstore_k<<<192, 256, 0, stream>>>(ref3, 676, 768, nullptr, nullptr, nref3);

        // patch tensor, two halves padded to 28928 rows (113 chunks of 256;
        // nch = 4 x 256 cols, U = 452, grid = 8*ceil(452/8) = 456)
        for (int h = 0; h < 2; h++) {
            const float* src = patch + (size_t)h * 28800 * D;
            normstore_k<<<7232, 256, 0, stream>>>(src, 28800, 28928, nullptr, nullptr, Abuf);
            gemm_max8_k<<<456, 512, 0, stream>>>(Abuf, nrefP, 4, 452, partial);
            reducemax_k<<<113, 256, 0, stream>>>(partial, 16, 28800, vasP + h * 28800);
        }
        // w2 tensor (196 chunks x 4 = U 784)
        normstore_k<<<12544, 256, 0, stream>>>(w2, 50176, 50176, tn, zs2, Abuf);
        gemm_max8_k<<<784, 512, 0, stream>>>(Abuf, nref2, 4, 784, partial);
        reducemax_k<<<196, 256, 0, stream>>>(partial, 16, 50176, vas2);
        // w3 tensor (169 chunks x 3 = U 507, grid 512)
        normstore_k<<<10816, 256, 0, stream>>>(w3, 43264, 43264, tn, zs3, Abuf);
        gemm_max8_k<<<512, 512, 0, stream>>>(Abuf, nref3, 3, 507, partial);
        reducemax_k<<<169, 256, 0, stream>>>(partial, 12, 43264, vas3);

        fuse_k<<<256, 256, 0, stream>>>(imgsc, zs2, zs3, vasP, vas2, vas3, multi, out_img);
        resize_k<<<57600, 256, 0, stream>>>(multi, out_pix);
    } else {
        // fallback: round-1 passing path (~5.6 MB ws)
        float* tn    = (float*)alloc(2 * 640 * 4);
        float* imgsc = (float*)alloc(256 * 4);
        float* rn2   = (float*)alloc(50176 * 4);
        float* rn3   = (float*)alloc(43264 * 4);
        float* rnp   = (float*)alloc(57600 * 4);
        float* zs2   = (float*)alloc(50176 * 4);
        float* zs3   = (float*)alloc(43264 * 4);
        short* nrefP = (short*)alloc(960 * 640 * 2);
        short* nref2 = (short*)alloc(832 * 640 * 2);
        short* nref3 = (short*)alloc(704 * 640 * 2);
        float* vasP  = (float*)alloc(57600 * 4);
        float* vas2  = (float*)alloc(50176 * 4);
        float* vas3  = (float*)alloc(43264 * 4);
        float* multi = (float*)alloc(57600 * 4);

        textnorm_k<<<1, 128, 0, stream>>>(text, tn);
        rowstats_k<<<64, 256, 0, stream>>>(image, 256, tn, nullptr, imgsc);
        rowstats_k<<<12544, 256, 0, stream>>>(w2, 50176, tn, rn2, zs2);
        rowstats_k<<<10816, 256, 0, stream>>>(w3, 43264, tn, rn3, zs3);
        rowstats_k<<<14400, 256, 0, stream>>>(patch, 57600, nullptr, rnp, nullptr);
        refnorm_k<<<240, 256, 0, stream>>>(refP, 900, 960, nrefP);
        refnorm_k<<<208, 256, 0, stream>>>(ref2, 784, 832, nref2);
        refnorm_k<<<176, 256, 0, stream>>>(ref3, 676, 704, nref3);
        maxcos_k<<<900, 256, 0, stream>>>(patch, rnp, nrefP, 960, vasP);
        maxcos_k<<<784, 256, 0, stream>>>(w2, rn2, nref2, 832, vas2);
        maxcos_k<<<676, 256, 0, stream>>>(w3, rn3, nref3, 704, vas3);
        fuse_k<<<256, 256, 0, stream>>>(imgsc, zs2, zs3, vasP, vas2, vas3, multi, out_img);
        resize_k<<<57600, 256, 0, stream>>>(multi, out_pix);
    }
}

// Round 16
// 382.565 us; speedup vs baseline: 1.0946x; 1.0946x over previous
//
#include <hip/hip_runtime.h>
#include <cmath>

#define D 640
#define TEMP_INV (1.0f / 0.07f)

typedef __attribute__((ext_vector_type(8))) short bf16x8;
typedef __attribute__((ext_vector_type(4))) float f32x4;

__device__ __forceinline__ short f2bf(float f) {
    unsigned int u = __float_as_uint(f);
    unsigned int r = (u + 0x7fffu + ((u >> 16) & 1u)) >> 16;   // RNE bf16
    return (short)r;
}

__device__ __forceinline__ void gload_lds16(const void* g, void* l) {
    __builtin_amdgcn_global_load_lds(
        (const __attribute__((address_space(1))) unsigned int*)g,
        (__attribute__((address_space(3))) unsigned int*)l, 16, 0, 0);
}

// ---------------------------------------------------------------- text norm
__global__ void textnorm_k(const float* __restrict__ T, float* __restrict__ tn) {
    int w = threadIdx.x >> 6, lane = threadIdx.x & 63;
    const float* row = T + w * D;
    float v[10]; float ss = 0.f;
#pragma unroll
    for (int i = 0; i < 10; i++) { v[i] = row[lane + 64 * i]; ss += v[i] * v[i]; }
#pragma unroll
    for (int m = 1; m < 64; m <<= 1) ss += __shfl_xor(ss, m, 64);
    float rn = 1.f / fmaxf(sqrtf(ss), 1e-12f);
#pragma unroll
    for (int i = 0; i < 10; i++) tn[w * D + lane + 64 * i] = v[i] * rn;
}

// ---------------- fused: row norm + text score + normalized-bf16 store (padded)
__global__ __launch_bounds__(256) void normstore_k(
    const float* __restrict__ X, int nsrc, int npad, const float* __restrict__ tn,
    float* __restrict__ score_out, short* __restrict__ bf16_out) {
    int wid = blockIdx.x * 4 + (threadIdx.x >> 6);
    int lane = threadIdx.x & 63;
    if (wid >= npad) return;
    const float2* row = (const float2*)(X + (size_t)(wid < nsrc ? wid : 0) * D);
    const float2* t0 = (const float2*)tn;
    const float2* t1 = (const float2*)(tn + D);
    float2 v[5]; float ss = 0.f, d0 = 0.f, d1 = 0.f;
#pragma unroll
    for (int i = 0; i < 5; i++) {
        float2 a = row[lane + 64 * i];
        v[i] = a;
        ss += a.x * a.x + a.y * a.y;
        if (tn) {
            float2 b0 = t0[lane + 64 * i], b1 = t1[lane + 64 * i];
            d0 += a.x * b0.x + a.y * b0.y;
            d1 += a.x * b1.x + a.y * b1.y;
        }
    }
#pragma unroll
    for (int m = 1; m < 64; m <<= 1) {
        ss += __shfl_xor(ss, m, 64);
        if (tn) { d0 += __shfl_xor(d0, m, 64); d1 += __shfl_xor(d1, m, 64); }
    }
    float rn = 1.f / fmaxf(sqrtf(ss), 1e-12f);
    if (score_out && lane == 0)
        score_out[wid] = 1.f / (1.f + expf(-((d1 - d0) * rn) * TEMP_INV));
    if (bf16_out) {
        ushort2* o = (ushort2*)bf16_out;
#pragma unroll
        for (int i = 0; i < 5; i++) {
            ushort2 p;
            p.x = (unsigned short)f2bf(v[i].x * rn);
            p.y = (unsigned short)f2bf(v[i].y * rn);
            o[(size_t)wid * 320 + lane + 64 * i] = p;
        }
    }
}

// --------------- GEMM + per-unit per-wave max partials (converged structure)
// A: [nrc*128 x 640] bf16; B: [nch*128 x 640] bf16. Tile = 128 x 128, BK=64,
// 4 waves (2M x 2N), 32 KB LDS, launch_bounds(256,4) -> 4 blocks/CU.
// Session-verified optimum: r13's (256,5) spilled acc to scratch (343 MB
// writes); r9/r10 counted-vmcnt variants lost occupancy/amortization;
// r15's fine-phase 256^2 (1 block/CU) gated on phase barriers. One unit per
// block: (g=bid&7, ii=bid>>3) owns unit ulo+ii of XCD g's slab. T5 setprio.
// partial[row*(2*nch) + nc*2 + wc] = per-wave 64-col max.
__global__ __launch_bounds__(256, 4) void gemm_max_k(
    const short* __restrict__ A, const short* __restrict__ B,
    int nch, int U, float* __restrict__ partial) {
    __shared__ short Al[128 * 64];
    __shared__ short Bl[128 * 64];
    const int t = threadIdx.x;
    const int g = blockIdx.x & 7, ii = blockIdx.x >> 3;
    const int ulo = (int)(((long long)g * U) >> 3);
    const int uhi = (int)(((long long)(g + 1) * U) >> 3);
    const int u = ulo + ii;
    if (u >= uhi) return;
    const int rc = u / nch, nc = u - rc * nch;
    const int nchq = nch * 2;

    // staging geometry: linear LDS dest (t*16), inverse-XOR-swizzled source
    const int srow = t >> 3;                               // 0..31, + i*32
    const int scol = (t & 7) * 16;                         // byte within 128B row
    const int gsw = (scol ^ ((srow & 7) << 4)) >> 1;       // shorts

    const int lane = t & 63, wave = t >> 6;
    const int l15 = lane & 15, lhi = lane >> 4;
    const int wr = wave >> 1, wc = wave & 1;               // 2M x 2N wave grid
    const int xk = (l15 & 7) << 4;                         // read-side swizzle

    char* Ab = (char*)Al;
    char* Bb = (char*)Bl;
    char* Ad = Ab + t * 16;
    char* Bd = Bb + t * 16;

    // per-lane row (srow) INCLUDED in global source
    const short* Ag = A + ((size_t)rc * 128 + srow) * D + gsw;
    const short* Bg = B + ((size_t)nc * 128 + srow) * D + gsw;

    f32x4 acc[4][4];
#pragma unroll
    for (int m = 0; m < 4; m++)
#pragma unroll
        for (int n = 0; n < 4; n++) acc[m][n] = (f32x4){0.f, 0.f, 0.f, 0.f};

    for (int ks = 0; ks < 10; ks++) {
        const int k0 = ks * 64;
        __syncthreads();                     // previous tile fully consumed
#pragma unroll
        for (int i = 0; i < 4; i++)
            gload_lds16(Ag + k0 + (size_t)(i * 32) * D, Ad + i * 4096);
#pragma unroll
        for (int i = 0; i < 4; i++)
            gload_lds16(Bg + k0 + (size_t)(i * 32) * D, Bd + i * 4096);
        __syncthreads();                     // drains vmcnt: tile ready
        __builtin_amdgcn_s_setprio(1);
#pragma unroll
        for (int sub = 0; sub < 2; sub++) {
            const int kbs = (sub * 64 + lhi * 16) ^ xk;
            bf16x8 a[4], b[4];
#pragma unroll
            for (int m = 0; m < 4; m++)
                a[m] = *(const bf16x8*)(Ab + (wr * 64 + m * 16 + l15) * 128 + kbs);
#pragma unroll
            for (int n = 0; n < 4; n++)
                b[n] = *(const bf16x8*)(Bb + (wc * 64 + n * 16 + l15) * 128 + kbs);
#pragma unroll
            for (int m = 0; m < 4; m++)
#pragma unroll
                for (int n = 0; n < 4; n++)
                    acc[m][n] = __builtin_amdgcn_mfma_f32_16x16x32_bf16(a[m], b[n], acc[m][n], 0, 0, 0);
        }
        __builtin_amdgcn_s_setprio(0);
    }

    // epilogue: per-row max over this wave's 64 cols -> partial
#pragma unroll
    for (int m = 0; m < 4; m++)
#pragma unroll
        for (int r = 0; r < 4; r++) {
            float v = fmaxf(fmaxf(acc[m][0][r], acc[m][1][r]),
                            fmaxf(acc[m][2][r], acc[m][3][r]));
#pragma unroll
            for (int msk = 1; msk < 16; msk <<= 1)
                v = fmaxf(v, __shfl_xor(v, msk, 64));
            if (l15 == 0) {
                int row = rc * 128 + wr * 64 + m * 16 + lhi * 4 + r;
                partial[(size_t)row * nchq + nc * 2 + wc] = v;
            }
        }
}

// ------------------------------------------------ reduce partials -> vas score
__global__ __launch_bounds__(256) void reducemax_k(
    const float* __restrict__ partial, int nchq, int nrows, float* __restrict__ vas) {
    int r = blockIdx.x * 256 + threadIdx.x;
    if (r >= nrows) return;
    float m = -1e30f;
    for (int i = 0; i < nchq; i++) m = fmaxf(m, partial[(size_t)r * nchq + i]);
    vas[r] = (1.0f - m) * 0.5f;
}

// =================== OLD (round-1) fallback path kernels =====================
__global__ __launch_bounds__(256) void rowstats_k(
    const float* __restrict__ X, int nrows, const float* __restrict__ tn,
    float* __restrict__ rnorm_out, float* __restrict__ score_out) {
    int wid = blockIdx.x * 4 + (threadIdx.x >> 6);
    int lane = threadIdx.x & 63;
    if (wid >= nrows) return;
    const float* row = X + (size_t)wid * D;
    float ss = 0.f, d0 = 0.f, d1 = 0.f;
#pragma unroll
    for (int i = 0; i < 10; i++) {
        float v = row[lane + 64 * i];
        ss += v * v;
        if (tn) { d0 += v * tn[lane + 64 * i]; d1 += v * tn[D + lane + 64 * i]; }
    }
#pragma unroll
    for (int m = 1; m < 64; m <<= 1) {
        ss += __shfl_xor(ss, m, 64);
        if (tn) { d0 += __shfl_xor(d0, m, 64); d1 += __shfl_xor(d1, m, 64); }
    }
    if (lane == 0) {
        float rn = 1.f / fmaxf(sqrtf(ss), 1e-12f);
        if (rnorm_out) rnorm_out[wid] = rn;
        if (score_out) score_out[wid] = 1.f / (1.f + expf(-((d1 - d0) * rn) * TEMP_INV));
    }
}

__global__ __launch_bounds__(256) void refnorm_k(
    const float* __restrict__ R, int M, int Mp, short* __restrict__ out) {
    int wid = blockIdx.x * 4 + (threadIdx.x >> 6);
    int lane = threadIdx.x & 63;
    if (wid >= Mp) return;
    const float* row = R + (size_t)(wid < M ? wid : 0) * D;
    float v[10]; float ss = 0.f;
#pragma unroll
    for (int i = 0; i < 10; i++) { v[i] = row[lane + 64 * i]; ss += v[i] * v[i]; }
#pragma unroll
    for (int m = 1; m < 64; m <<= 1) ss += __shfl_xor(ss, m, 64);
    float rn = 1.f / fmaxf(sqrtf(ss), 1e-12f);
#pragma unroll
    for (int i = 0; i < 10; i++) out[(size_t)wid * D + lane + 64 * i] = f2bf(v[i] * rn);
}

#define SA 648
#define SB 72
__global__ __launch_bounds__(256) void maxcos_k(
    const float* __restrict__ X, const float* __restrict__ rnorm,
    const short* __restrict__ refs, int Mp, float* __restrict__ vas_out) {
    __shared__ short Alds[64 * SA];
    __shared__ short Blds[64 * SB];
    const int t = threadIdx.x;
    const size_t rowBase = (size_t)blockIdx.x * 64;
#pragma unroll
    for (int i = 0; i < 20; i++) {
        int c = i * 256 + t;
        int row = c / 80, col = (c % 80) * 8;
        const float* p = X + (rowBase + row) * D + col;
        float rn = rnorm[rowBase + row];
        float4 v0 = *(const float4*)p;
        float4 v1 = *(const float4*)(p + 4);
        bf16x8 s;
        s[0] = f2bf(v0.x * rn); s[1] = f2bf(v0.y * rn);
        s[2] = f2bf(v0.z * rn); s[3] = f2bf(v0.w * rn);
        s[4] = f2bf(v1.x * rn); s[5] = f2bf(v1.y * rn);
        s[6] = f2bf(v1.z * rn); s[7] = f2bf(v1.w * rn);
        *(bf16x8*)&Alds[row * SA + col] = s;
    }
    __syncthreads();
    const int lane = t & 63, wave = t >> 6;
    const int l15 = lane & 15, lhi = lane >> 4;
    const int wr0 = wave * 16;
    float rowmax[4] = {-1e30f, -1e30f, -1e30f, -1e30f};
    for (int m0 = 0; m0 < Mp; m0 += 64) {
        f32x4 zero = {0.f, 0.f, 0.f, 0.f};
        f32x4 acc[4] = {zero, zero, zero, zero};
        for (int ks = 0; ks < 10; ks++) {
            __syncthreads();
#pragma unroll
            for (int c2 = 0; c2 < 2; c2++) {
                int c = c2 * 256 + t;
                int n = c >> 3, kk = (c & 7) * 8;
                const short* g = refs + (size_t)(m0 + n) * D + ks * 64 + kk;
                *(bf16x8*)&Blds[n * SB + kk] = *(const bf16x8*)g;
            }
            __syncthreads();
#pragma unroll
            for (int sub = 0; sub < 2; sub++) {
                bf16x8 a = *(const bf16x8*)&Alds[(wr0 + l15) * SA + ks * 64 + sub * 32 + lhi * 8];
#pragma unroll
                for (int s = 0; s < 4; s++) {
                    bf16x8 b = *(const bf16x8*)&Blds[(s * 16 + l15) * SB + sub * 32 + lhi * 8];
                    acc[s] = __builtin_amdgcn_mfma_f32_16x16x32_bf16(a, b, acc[s], 0, 0, 0);
                }
            }
        }
#pragma unroll
        for (int r = 0; r < 4; r++) {
            float mv = fmaxf(fmaxf(acc[0][r], acc[1][r]), fmaxf(acc[2][r], acc[3][r]));
#pragma unroll
            for (int msk = 1; msk < 16; msk <<= 1) mv = fmaxf(mv, __shfl_xor(mv, msk, 64));
            rowmax[r] = fmaxf(rowmax[r], mv);
        }
    }
    if (l15 == 0) {
#pragma unroll
        for (int r = 0; r < 4; r++) {
            size_t row = rowBase + wr0 + lhi * 4 + r;
            vas_out[row] = (1.0f - rowmax[r]) * 0.5f;
        }
    }
}

// ------------------------------------- harmonic aggregation + fusion + max
__global__ __launch_bounds__(256) void fuse_k(
    const float* __restrict__ imgsc, const float* __restrict__ zs2,
    const float* __restrict__ zs3, const float* __restrict__ vasP,
    const float* __restrict__ vas2, const float* __restrict__ vas3,
    float* __restrict__ multi, float* __restrict__ img_out) {
    int b = blockIdx.x, t = threadIdx.x;
    __shared__ float red[256];
    float few = -1e30f;
    if (t < 225) {
        int i = t / 15, j = t % 15;
        float invz2 = 0.f, invf2 = 0.f; int c2 = 0;
        int ilo = max(0, i - 1), ihi = min(i, 13), jlo = max(0, j - 1), jhi = min(j, 13);
        for (int i0 = ilo; i0 <= ihi; i0++)
            for (int j0 = jlo; j0 <= jhi; j0++) {
                int w = b * 196 + i0 * 14 + j0;
                invz2 += 1.f / zs2[w]; invf2 += 1.f / vas2[w]; c2++;
            }
        float zh2 = (float)c2 / invz2, fh2 = (float)c2 / invf2;
        float invz3 = 0.f, invf3 = 0.f; int c3 = 0;
        ilo = max(0, i - 2); ihi = min(i, 12); jlo = max(0, j - 2); jhi = min(j, 12);
        for (int i0 = ilo; i0 <= ihi; i0++)
            for (int j0 = jlo; j0 <= jhi; j0++) {
                int w = b * 169 + i0 * 13 + j0;
                invz3 += 1.f / zs3[w]; invf3 += 1.f / vas3[w]; c3++;
            }
        float zh3 = (float)c3 / invz3, fh3 = (float)c3 / invf3;
        float is = imgsc[b];
        float zero_shot = 3.f / (1.f / is + 1.f / zh2 + 1.f / zh3);
        float fs0 = vasP[b * 225 + t];
        few = (fs0 + fh2 + fh3) * (1.f / 3.f);
        multi[b * 225 + t] = (zero_shot + few) * 0.5f;
    }
    red[t] = few;
    __syncthreads();
    for (int s = 128; s > 0; s >>= 1) {
        if (t < s) red[t] = fmaxf(red[t], red[t + s]);
        __syncthreads();
    }
    if (t == 0) img_out[b] = (imgsc[b] + red[0]) * 0.5f;
}

// ----------------------------------- bilinear resize 15x15 -> 240x240 (clamp)
__global__ __launch_bounds__(256) void resize_k(
    const float* __restrict__ multi, float* __restrict__ out) {
    int idx = blockIdx.x * 256 + threadIdx.x;
    int x = idx % 240;
    int rest = idx / 240;
    int y = rest % 240;
    int b = rest / 240;
    float sx = (x + 0.5f) * 0.0625f - 0.5f;
    float sy = (y + 0.5f) * 0.0625f - 0.5f;
    sx = fminf(fmaxf(sx, 0.f), 14.f);
    sy = fminf(fmaxf(sy, 0.f), 14.f);
    int x0 = min((int)sx, 13), y0 = min((int)sy, 13);
    float fx = sx - x0, fy = sy - y0;
    const float* m = multi + b * 225;
    float v00 = m[y0 * 15 + x0],      v01 = m[y0 * 15 + x0 + 1];
    float v10 = m[y0 * 15 + 15 + x0], v11 = m[y0 * 15 + 15 + x0 + 1];
    out[idx] = (1.f - fy) * ((1.f - fx) * v00 + fx * v01)
             + fy * ((1.f - fx) * v10 + fx * v11);
}

// ---------------------------------------------------------------------------
extern "C" void kernel_launch(void* const* d_in, const int* in_sizes, int n_in,
                              void* d_out, int out_size, void* d_ws, size_t ws_size,
                              hipStream_t stream) {
    const float* image = (const float*)d_in[0];
    const float* w2    = (const float*)d_in[1];
    const float* w3    = (const float*)d_in[2];
    const float* patch = (const float*)d_in[3];
    const float* text  = (const float*)d_in[4];
    const float* refP  = (const float*)d_in[5];
    const float* ref2  = (const float*)d_in[6];
    const float* ref3  = (const float*)d_in[7];
    float* out_img = (float*)d_out;
    float* out_pix = out_img + 256;

    char* wsb = (char*)d_ws;
    size_t off = 0;
    auto alloc = [&](size_t bytes) -> void* {
        void* p = wsb + off;
        off += (bytes + 255) & ~(size_t)255;
        return p;
    };

    // new-path workspace need (~72.3 MB, below known-safe 80.2 MB floor)
    const size_t NEW_NEED = 72300000;
    if (ws_size >= NEW_NEED) {
        float* tn    = (float*)alloc(2 * 640 * 4);
        float* imgsc = (float*)alloc(256 * 4);
        float* zs2   = (float*)alloc(50176 * 4);
        float* zs3   = (float*)alloc(43264 * 4);
        short* nrefP = (short*)alloc(1024 * 640 * 2);
        short* nref2 = (short*)alloc(896 * 640 * 2);
        short* nref3 = (short*)alloc(768 * 640 * 2);
        short* Abuf  = (short*)alloc((size_t)50176 * 640 * 2);
        float* partial = (float*)alloc((size_t)50176 * 16 * 4);
        float* vasP  = (float*)alloc(57600 * 4);
        float* vas2  = (float*)alloc(50176 * 4);
        float* vas3  = (float*)alloc(43264 * 4);
        float* multi = (float*)alloc(57600 * 4);

        textnorm_k<<<1, 128, 0, stream>>>(text, tn);
        normstore_k<<<64, 256, 0, stream>>>(image, 256, 256, tn, imgsc, nullptr);
        normstore_k<<<256, 256, 0, stream>>>(refP, 900, 1024, nullptr, nullptr, nrefP);
        normstore_k<<<224, 256, 0, stream>>>(ref2, 784, 896, nullptr, nullptr, nref2);
        normstore_k<<<192, 256, 0, stream>>>(ref3, 676, 768, nullptr, nullptr, nref3);

        // patch tensor, two 28800-row halves (nrc=225, nch=8 x 128 cols, U=1800)
        for (int h = 0; h < 2; h++) {
            const float* src = patch + (size_t)h * 28800 * D;
            normstore_k<<<7200, 256, 0, stream>>>(src, 28800, 28800, nullptr, nullptr, Abuf);
            gemm_max_k<<<1800, 256, 0, stream>>>(Abuf, nrefP, 8, 1800, partial);
            reducemax_k<<<113, 256, 0, stream>>>(partial, 16, 28800, vasP + h * 28800);
        }
        // w2 tensor (nrc=392, nch=7 x 128 cols, U=2744)
        normstore_k<<<12544, 256, 0, stream>>>(w2, 50176, 50176, tn, zs2, Abuf);
        gemm_max_k<<<2744, 256, 0, stream>>>(Abuf, nref2, 7, 2744, partial);
        reducemax_k<<<196, 256, 0, stream>>>(partial, 14, 50176, vas2);
        // w3 tensor (nrc=338, nch=6 x 128 cols, U=2028; grid 8*ceil(2028/8)=2032)
        normstore_k<<<10816, 256, 0, stream>>>(w3, 43264, 43264, tn, zs3, Abuf);
        gemm_max_k<<<2032, 256, 0, stream>>>(Abuf, nref3, 6, 2028, partial);
        reducemax_k<<<169, 256, 0, stream>>>(partial, 12, 43264, vas3);

        fuse_k<<<256, 256, 0, stream>>>(imgsc, zs2, zs3, vasP, vas2, vas3, multi, out_img);
        resize_k<<<57600, 256, 0, stream>>>(multi, out_pix);
    } else {
        // fallback: round-1 passing path (~5.6 MB ws)
        float* tn    = (float*)alloc(2 * 640 * 4);
        float* imgsc = (float*)alloc(256 * 4);
        float* rn2   = (float*)alloc(50176 * 4);
        float* rn3   = (float*)alloc(43264 * 4);
        float* rnp   = (float*)alloc(57600 * 4);
        float* zs2   = (float*)alloc(50176 * 4);
        float* zs3   = (float*)alloc(43264 * 4);
        short* nrefP = (short*)alloc(960 * 640 * 2);
        short* nref2 = (short*)alloc(832 * 640 * 2);
        short* nref3 = (short*)alloc(704 * 640 * 2);
        float* vasP  = (float*)alloc(57600 * 4);
        float* vas2  = (float*)alloc(50176 * 4);
        float* vas3  = (float*)alloc(43264 * 4);
        float* multi = (float*)alloc(57600 * 4);

        textnorm_k<<<1, 128, 0, stream>>>(text, tn);
        rowstats_k<<<64, 256, 0, stream>>>(image, 256, tn, nullptr, imgsc);
        rowstats_k<<<12544, 256, 0, stream>>>(w2, 50176, tn, rn2, zs2);
        rowstats_k<<<10816, 256, 0, stream>>>(w3, 43264, tn, rn3, zs3);
        rowstats_k<<<14400, 256, 0, stream>>>(patch, 57600, nullptr, rnp, nullptr);
        refnorm_k<<<240, 256, 0, stream>>>(refP, 900, 960, nrefP);
        refnorm_k<<<208, 256, 0, stream>>>(ref2, 784, 832, nref2);
        refnorm_k<<<176, 256, 0, stream>>>(ref3, 676, 704, nref3);
        maxcos_k<<<900, 256, 0, stream>>>(patch, rnp, nrefP, 960, vasP);
        maxcos_k<<<784, 256, 0, stream>>>(w2, rn2, nref2, 832, vas2);
        maxcos_k<<<676, 256, 0, stream>>>(w3, rn3, nref3, 704, vas3);
        fuse_k<<<256, 256, 0, stream>>>(imgsc, zs2, zs3, vasP, vas2, vas3, multi, out_img);
        resize_k<<<57600, 256, 0, stream>>>(multi, out_pix);
    }
}